// Round 1
// baseline (23809.537 us; speedup 1.0000x reference)
//
#include <hip/hip_runtime.h>
#include <stdint.h>

// Problem constants
#define kS 256      // sequence length
#define kB 256      // batch
#define kE 300      // embedding dim
#define kH 300      // hidden per direction
#define kG 1200     // 4*H gate rows
#define kT 9        // tags

// Decomposition: each (dir, 4-batch tile) is computed by 2 partner blocks,
// each owning 600 gate rows (= 150 hidden units x 4 gates). Per-step h
// exchange between partners via agent-scope atomics (no fences -> L2 weight
// cache stays intact). 256 blocks x 640 threads, 1 block/CU, 10 waves/CU.
#define ROWS 600        // gate rows per block
#define TILE_B 4        // batch rows per group
#define TCHUNK 8        // timesteps per input-projection chunk
#define NTH 640         // threads per block (10 waves)
#define SLICE_F4 45000  // 75 * 600 float4 per weight slice
#define EMSZ (kS * kB * kT)

__device__ __forceinline__ float sigmoidf_(float v) { return 1.0f / (1.0f + expf(-v)); }

// -----------------------------------------------------------------------------
// Pre-pass: transpose [1200][300] weights into per-split k-major float4 layout.
// Slice q holds rows r = gate*300 + q*150 + i (gate-major within slice), laid
// out wt[q][kc][rr] so consecutive threads (consecutive rr) read consecutive
// 16B -> coalesced. Also zeroes the exchange flags (must happen every launch).
// -----------------------------------------------------------------------------
__global__ __launch_bounds__(256) void transpose_w_all(
    const float* __restrict__ w_ih_f, const float* __restrict__ w_hh_f,
    const float* __restrict__ w_ih_b, const float* __restrict__ w_hh_b,
    float4* __restrict__ wt, int* __restrict__ flags)
{
    const int m = blockIdx.y;  // 0: ih_f, 1: hh_f, 2: ih_b, 3: hh_b
    const float* w = (m == 0) ? w_ih_f : (m == 1) ? w_hh_f : (m == 2) ? w_ih_b : w_hh_b;
    if (blockIdx.y == 0 && blockIdx.x == 0) flags[threadIdx.x] = 0;
    int i = blockIdx.x * 256 + threadIdx.x;
    if (i >= 2 * SLICE_F4) return;
    const int q    = i / SLICE_F4;
    const int rem  = i - q * SLICE_F4;
    const int kc   = rem / ROWS;
    const int rr   = rem - kc * ROWS;
    const int gate = rr / 150;
    const int ii   = rr - gate * 150;
    const int r    = gate * 300 + q * 150 + ii;
    const float* p = w + (size_t)r * 300 + kc * 4;
    wt[(size_t)m * 2 * SLICE_F4 + i] = make_float4(p[0], p[1], p[2], p[3]);
}

// 5-kc group load (prefetch one group ahead of compute)
#define LOAD5(W) { _Pragma("unroll") for (int j = 0; j < 5; ++j) W[j] = wl[j * ROWS]; wl += 5 * ROWS; }

#define HH_STEP(W, KCB) \
  _Pragma("unroll") \
  for (int j = 0; j < 5; ++j) { \
    const int k4 = ((KCB) + j) * 4; \
    const float4 h0 = *(const float4*)&s_h[0][k4]; \
    const float4 h1 = *(const float4*)&s_h[1][k4]; \
    const float4 h2 = *(const float4*)&s_h[2][k4]; \
    const float4 h3 = *(const float4*)&s_h[3][k4]; \
    a0 += W[j].x*h0.x + W[j].y*h0.y + W[j].z*h0.z + W[j].w*h0.w; \
    a1 += W[j].x*h1.x + W[j].y*h1.y + W[j].z*h1.z + W[j].w*h1.w; \
    a2 += W[j].x*h2.x + W[j].y*h2.y + W[j].z*h2.z + W[j].w*h2.w; \
    a3 += W[j].x*h3.x + W[j].y*h3.y + W[j].z*h3.z + W[j].w*h3.w; \
  }

#define IH_STEP(W, KCB) \
  _Pragma("unroll") \
  for (int j = 0; j < 5; ++j) { \
    const int k4 = ((KCB) + j) * 4; \
    _Pragma("unroll") \
    for (int u = 0; u < 32; ++u) { \
      const float4 a = *(const float4*)&s_Ax[u][k4]; \
      acc[u] += W[j].x*a.x + W[j].y*a.y + W[j].z*a.z + W[j].w*a.w; \
    } \
  }

// -----------------------------------------------------------------------------
// Fused BiLSTM, split-pair version.
//  block -> (dir, q, tile): xcd = bi&7: dir=xcd>>2, q=(xcd>>1)&1, so each XCD
//  hosts one (dir,q) combo -> 1.44 MB weight working set per XCD L2.
//  Partner blocks (same dir,tile; q vs 1-q) exchange their 150-unit h slice
//  every step through hxh (parity double-buffered) + monotonic step flags.
//  All exchange traffic uses agent-scope relaxed atomics (per-access coherent,
//  bypasses L1/L2) -- NO acquire/release fences, so no buffer_inv/wbl2 that
//  would flush the streamed weights out of L2.
// -----------------------------------------------------------------------------
__global__ __launch_bounds__(NTH, 3) void ner_bilstm_kernel(
    const int*    __restrict__ x,
    const float*  __restrict__ emb,
    const float4* __restrict__ wt,       // 4 matrices x 2 slices, k-major
    const float*  __restrict__ bih_f, const float* __restrict__ bhh_f,
    const float*  __restrict__ bih_b, const float* __restrict__ bhh_b,
    const float*  __restrict__ w_proj,   // [9][600]
    float*        __restrict__ em_all,   // 2 dir slabs [S][B][9]
    float*        __restrict__ hxh,      // h exchange: [gid2+q][2][600]
    float*        __restrict__ hxa,      // em-partial exchange: [gid2+q][2][40]
    int*          __restrict__ flags)    // [256] step counters
{
    extern __shared__ float s_pre[];                 // [32][600] = 76.8 KB
    __shared__ float s_Ax[32][304];                  // gathered embeddings
    __shared__ float s_h[TILE_B][304];               // full h_{t-1} (both halves)
    __shared__ float s_c[TILE_B][152];               // own 150 c values
    __shared__ float s_gbuf[TILE_B][ROWS];           // own gate preacts
    __shared__ float s_emp[TILE_B][kT][10];          // emission partial chunks
    __shared__ float s_emf[40], s_emf2[40];          // reduced partials (q0)
    // total LDS ~134 KB -> 1 block/CU.

    const int bi   = blockIdx.x;
    const int xcd  = bi & 7;
    const int dir  = xcd >> 2;
    const int q    = (xcd >> 1) & 1;
    const int tile = (bi >> 3) * 2 + (xcd & 1);      // 0..63
    const int tid  = threadIdx.x;

    const float4* wih4 = wt + ((size_t)(dir * 2 + 0)) * 2 * SLICE_F4 + (size_t)q * SLICE_F4;
    const float4* whh4 = wt + ((size_t)(dir * 2 + 1)) * 2 * SLICE_F4 + (size_t)q * SLICE_F4;
    const float*  bih  = dir ? bih_b : bih_f;
    const float*  bhh  = dir ? bhh_b : bhh_f;
    float* emout = em_all + (size_t)dir * EMSZ;

    const int gid2 = (dir * 64 + tile) * 2;
    float* hx_own  = hxh + (size_t)(gid2 + q)       * 2 * ROWS;
    float* hx_par  = hxh + (size_t)(gid2 + (1 - q)) * 2 * ROWS;
    float* hxa_own = hxa + (size_t)(gid2 + q)       * 2 * 40;
    float* hxa_par = hxa + (size_t)(gid2 + (1 - q)) * 2 * 40;
    int* flag_own  = flags + gid2 + q;
    int* flag_par  = flags + gid2 + (1 - q);

    float bsum = 0.0f;
    if (tid < ROWS) {
        const int gate = tid / 150, ii = tid - gate * 150;
        const int r = gate * 300 + q * 150 + ii;
        bsum = bih[r] + bhh[r];
    }

    for (int i = tid; i < TILE_B * 304; i += NTH) (&s_h[0][0])[i] = 0.0f;
    for (int i = tid; i < TILE_B * 152; i += NTH) (&s_c[0][0])[i] = 0.0f;
    __syncthreads();

    for (int tc = 0; tc < kS / TCHUNK; ++tc) {
        // ---- embedding gather: 32 (tt,b2) rows, 20 lanes each ------------------
        {
            const int rr = tid / 20, ln = tid - rr * 20;
            const int tt = rr >> 2, b2 = rr & 3;
            const int t  = tc * TCHUNK + tt;
            const int s  = dir ? (kS - 1 - t) : t;
            const int token = x[(tile * TILE_B + b2) * kS + s];
            const float* erow = emb + (size_t)token * kE;
            for (int e = ln; e < kE; e += 20) s_Ax[rr][e] = erow[e];
        }
        __syncthreads();

        // ---- input projection: s_pre[u][rr] = bias + x_u . w_ih_slice[rr] ------
        if (tid < ROWS) {
            float acc[32];
#pragma unroll
            for (int u = 0; u < 32; ++u) acc[u] = bsum;
            const float4* wl = wih4 + tid;
            float4 wA[5], wB[5];
            LOAD5(wA);
            int kcb = 0;
            for (int gp = 0; gp < 7; ++gp) {
                LOAD5(wB);
                IH_STEP(wA, kcb);
                kcb += 5;
                LOAD5(wA);
                IH_STEP(wB, kcb);
                kcb += 5;
            }
            IH_STEP(wA, 70);
#pragma unroll
            for (int u = 0; u < 32; ++u) s_pre[u * ROWS + tid] = acc[u];
        }
        __syncthreads();

        // ---- recurrent steps ---------------------------------------------------
        for (int tt = 0; tt < TCHUNK; ++tt) {
            const int t   = tc * TCHUNK + tt;
            const int s   = dir ? (kS - 1 - t) : t;
            const int par = t & 1;

            if (tid < ROWS) {
                float a0 = s_pre[(tt * 4 + 0) * ROWS + tid];
                float a1 = s_pre[(tt * 4 + 1) * ROWS + tid];
                float a2 = s_pre[(tt * 4 + 2) * ROWS + tid];
                float a3 = s_pre[(tt * 4 + 3) * ROWS + tid];
                const float4* wl = whh4 + tid;
                float4 wA[5], wB[5];
                LOAD5(wA);
                int kcb = 0;
                for (int gp = 0; gp < 7; ++gp) {
                    LOAD5(wB);
                    HH_STEP(wA, kcb);
                    kcb += 5;
                    LOAD5(wA);
                    HH_STEP(wB, kcb);
                    kcb += 5;
                }
                HH_STEP(wA, 70);
                s_gbuf[0][tid] = a0; s_gbuf[1][tid] = a1;
                s_gbuf[2][tid] = a2; s_gbuf[3][tid] = a3;
            }
            __syncthreads();

            // cell update for own 150 units x 4 batches; store h to exchange buf
            if (tid < ROWS) {
                const int b = tid / 150, i2 = tid - b * 150;
                const float gi = s_gbuf[b][i2];
                const float gf = s_gbuf[b][150 + i2];
                const float gg = s_gbuf[b][300 + i2];
                const float go = s_gbuf[b][450 + i2];
                const float c  = sigmoidf_(gf) * s_c[b][i2] + sigmoidf_(gi) * tanhf(gg);
                const float h  = sigmoidf_(go) * tanhf(c);
                s_c[b][i2] = c;
                s_h[b][q * 150 + i2] = h;
                __hip_atomic_store(&hx_own[par * ROWS + tid], h,
                                   __ATOMIC_RELAXED, __HIP_MEMORY_SCOPE_AGENT);
            }
            __syncthreads();

            // emission partials over own slice
            if (tid < 360) {
                const int b = tid / 90, rem = tid - b * 90;
                const int tag = rem / 10, ch = rem - tag * 10;
                const int n0 = ch * 15;
                const float* wrow = w_proj + tag * (2 * kH) + dir * kH + q * 150 + n0;
                const float* hrow = &s_h[b][q * 150 + n0];
                float sum = 0.0f;
#pragma unroll
                for (int k2 = 0; k2 < 15; ++k2) sum += hrow[k2] * wrow[k2];
                s_emp[b][tag][ch] = sum;
            }
            __syncthreads();
            if (tid < 36) {
                const int b = tid / 9, tag = tid - b * 9;
                float v = 0.0f;
#pragma unroll
                for (int ch = 0; ch < 10; ++ch) v += s_emp[b][tag][ch];
                if (q) __hip_atomic_store(&hxa_own[par * 40 + tid], v,
                                          __ATOMIC_RELAXED, __HIP_MEMORY_SCOPE_AGENT);
                else   s_emf[tid] = v;
            }
            // each wave drains its own agent stores, barrier, then signal
            asm volatile("s_waitcnt vmcnt(0)" ::: "memory");
            __syncthreads();
            if (tid == 0) {
                __hip_atomic_store(flag_own, t + 1,
                                   __ATOMIC_RELAXED, __HIP_MEMORY_SCOPE_AGENT);
                int spins = 0;
                while (__hip_atomic_load(flag_par, __ATOMIC_RELAXED,
                                         __HIP_MEMORY_SCOPE_AGENT) < t + 1) {
                    __builtin_amdgcn_s_sleep(2);
                    if (++spins > (1 << 22)) break;   // hang safety
                }
            }
            __syncthreads();
            // pull partner's h half (+ partner emission partial for q0)
            if (tid < ROWS) {
                const int b = tid / 150, i2 = tid - b * 150;
                s_h[b][(1 - q) * 150 + i2] =
                    __hip_atomic_load(&hx_par[par * ROWS + tid],
                                      __ATOMIC_RELAXED, __HIP_MEMORY_SCOPE_AGENT);
            } else if (!q && tid < ROWS + 36) {
                s_emf2[tid - ROWS] =
                    __hip_atomic_load(&hxa_par[par * 40 + (tid - ROWS)],
                                      __ATOMIC_RELAXED, __HIP_MEMORY_SCOPE_AGENT);
            }
            __syncthreads();
            if (!q && tid < 36) {
                const int b = tid / 9, tag = tid - b * 9;
                emout[((size_t)s * kB + tile * TILE_B + b) * kT + tag] =
                    s_emf[tid] + s_emf2[tid];
            }
            // no extra barrier: next phase writes s_gbuf/s_Ax/s_pre, all of which
            // are separated from the reads above by >=2 barriers in the next step
        }
    }
}

// -----------------------------------------------------------------------------
// CRF Viterbi decode (unchanged). 9 lanes per batch row.
// -----------------------------------------------------------------------------
__global__ __launch_bounds__(256) void ner_viterbi_kernel(
    const float* __restrict__ em_all,
    const float* __restrict__ b_proj,
    const float* __restrict__ start_t,
    const float* __restrict__ end_t,
    const float* __restrict__ trans,
    int*         __restrict__ out)
{
    const float* em_f = em_all;
    const float* em_b = em_all + EMSZ;

    __shared__ uint8_t bp[kS - 1][28][kT];

    const int tid  = threadIdx.x;
    const int wave = tid >> 6;
    const int lane = tid & 63;
    const int g    = lane / kT;
    const int nx   = lane % kT;
    const bool active = (g < 7);
    const int gg   = wave * 7 + g;
    const int b    = blockIdx.x * 28 + (active ? gg : 0);
    const bool valid = active && (b < kB);
    const int beff = (b < kB) ? b : (kB - 1);
    const int base = g * kT;

    float tcol[kT];
#pragma unroll
    for (int p = 0; p < kT; ++p) tcol[p] = trans[p * kT + nx];
    const float bpj = b_proj[nx];

    float score = start_t[nx]
                + em_f[(size_t)beff * kT + nx]
                + em_b[(size_t)beff * kT + nx]
                + bpj;

    for (int t = 1; t < kS; ++t) {
        const size_t ei = ((size_t)t * kB + beff) * kT + nx;
        const float em = em_f[ei] + em_b[ei] + bpj;
        float best = -3.402823466e38f;
        int bidx = 0;
#pragma unroll
        for (int p = 0; p < kT; ++p) {
            const float sp = __shfl(score, base + p, 64);
            const float cand = sp + tcol[p];
            if (cand > best) { best = cand; bidx = p; }
        }
        if (valid) bp[t - 1][gg][nx] = (uint8_t)bidx;
        score = best + em;
    }

    score += end_t[nx];
    float best = -3.402823466e38f;
    int last = 0;
#pragma unroll
    for (int p = 0; p < kT; ++p) {
        const float sp = __shfl(score, base + p, 64);
        if (sp > best) { best = sp; last = p; }
    }

    __syncthreads();

    if (valid && nx == 0) {
        int cur = last;
        out[beff * kS + (kS - 1)] = cur;
        for (int t = kS - 2; t >= 0; --t) {
            cur = bp[t][gg][cur];
            out[beff * kS + t] = cur;
        }
    }
}

// -----------------------------------------------------------------------------
extern "C" void kernel_launch(void* const* d_in, const int* in_sizes, int n_in,
                              void* d_out, int out_size, void* d_ws, size_t ws_size,
                              hipStream_t stream) {
    const int*   x       = (const int*)  d_in[0];
    const float* emb     = (const float*)d_in[1];
    const float* w_ih_f  = (const float*)d_in[2];
    const float* w_hh_f  = (const float*)d_in[3];
    const float* b_ih_f  = (const float*)d_in[4];
    const float* b_hh_f  = (const float*)d_in[5];
    const float* w_ih_b  = (const float*)d_in[6];
    const float* w_hh_b  = (const float*)d_in[7];
    const float* b_ih_b  = (const float*)d_in[8];
    const float* b_hh_b  = (const float*)d_in[9];
    const float* w_proj  = (const float*)d_in[10];
    const float* b_proj  = (const float*)d_in[11];
    const float* start_t = (const float*)d_in[12];
    const float* end_t   = (const float*)d_in[13];
    const float* trans   = (const float*)d_in[14];

    // workspace: em (4.72 MB) | wt 4x2 slices (5.76 MB) | hxh (1.23 MB) |
    //            hxa (80 KB) | flags (1 KB)  => ~11.8 MB
    float*  em_all = (float*)d_ws;
    float4* wt     = (float4*)((char*)d_ws + (size_t)2 * EMSZ * 4);
    float*  hxh    = (float*)((char*)wt + (size_t)4 * 2 * SLICE_F4 * sizeof(float4));
    float*  hxa    = hxh + (size_t)256 * 2 * ROWS;
    int*    flags  = (int*)(hxa + (size_t)256 * 2 * 40);

    dim3 tgrid((2 * SLICE_F4 + 255) / 256, 4);
    transpose_w_all<<<tgrid, 256, 0, stream>>>(w_ih_f, w_hh_f, w_ih_b, w_hh_b, wt, flags);

    ner_bilstm_kernel<<<256, NTH, 32 * ROWS * sizeof(float), stream>>>(
        x, emb, wt, b_ih_f, b_hh_f, b_ih_b, b_hh_b, w_proj,
        em_all, hxh, hxa, flags);

    ner_viterbi_kernel<<<10, 256, 0, stream>>>(
        em_all, b_proj, start_t, end_t, trans, (int*)d_out);
}

// Round 2
// 13799.692 us; speedup vs baseline: 1.7254x; 1.7254x over previous
//
#include <hip/hip_runtime.h>
#include <stdint.h>

// Problem constants
#define kS 256      // sequence length
#define kB 256      // batch
#define kE 300      // embedding dim
#define kH 300      // hidden per direction
#define kG 1200     // 4*H gate rows
#define kT 9        // tags

// Decomposition: each (dir, 4-batch tile) is computed by 2 partner blocks,
// each owning 600 gate rows (= 150 hidden units x 4 gates). Per-step h
// exchange between partners via agent-scope atomics (no fences -> L2 weight
// cache stays intact). 256 blocks x 640 threads, 1 block/CU, 10 waves/CU.
#define ROWS 600        // gate rows per block
#define TILE_B 4        // batch rows per group
#define TCHUNK 8        // timesteps per input-projection chunk
#define NTH 640         // threads per block (10 waves)
#define SLICE_F4 45000  // 75 * 600 float4 per weight slice
#define EMSZ (kS * kB * kT)

__device__ __forceinline__ float sigmoidf_(float v) { return 1.0f / (1.0f + expf(-v)); }

// -----------------------------------------------------------------------------
// Pre-pass: transpose [1200][300] weights into per-split k-major float4 layout.
// -----------------------------------------------------------------------------
__global__ __launch_bounds__(256) void transpose_w_all(
    const float* __restrict__ w_ih_f, const float* __restrict__ w_hh_f,
    const float* __restrict__ w_ih_b, const float* __restrict__ w_hh_b,
    float4* __restrict__ wt, int* __restrict__ flags)
{
    const int m = blockIdx.y;  // 0: ih_f, 1: hh_f, 2: ih_b, 3: hh_b
    const float* w = (m == 0) ? w_ih_f : (m == 1) ? w_hh_f : (m == 2) ? w_ih_b : w_hh_b;
    if (blockIdx.y == 0 && blockIdx.x == 0) flags[threadIdx.x] = 0;
    int i = blockIdx.x * 256 + threadIdx.x;
    if (i >= 2 * SLICE_F4) return;
    const int q    = i / SLICE_F4;
    const int rem  = i - q * SLICE_F4;
    const int kc   = rem / ROWS;
    const int rr   = rem - kc * ROWS;
    const int gate = rr / 150;
    const int ii   = rr - gate * 150;
    const int r    = gate * 300 + q * 150 + ii;
    const float* p = w + (size_t)r * 300 + kc * 4;
    wt[(size_t)m * 2 * SLICE_F4 + i] = make_float4(p[0], p[1], p[2], p[3]);
}

// 5-kc group load (prefetch one group ahead of compute)
#define LOAD5(W) { _Pragma("unroll") for (int j = 0; j < 5; ++j) W[j] = wl[j * ROWS]; wl += 5 * ROWS; }

#define HH_STEP(W, KCB) \
  _Pragma("unroll") \
  for (int j = 0; j < 5; ++j) { \
    const int k4 = ((KCB) + j) * 4; \
    const float4 h0 = *(const float4*)&s_h[0][k4]; \
    const float4 h1 = *(const float4*)&s_h[1][k4]; \
    const float4 h2 = *(const float4*)&s_h[2][k4]; \
    const float4 h3 = *(const float4*)&s_h[3][k4]; \
    a0 += W[j].x*h0.x + W[j].y*h0.y + W[j].z*h0.z + W[j].w*h0.w; \
    a1 += W[j].x*h1.x + W[j].y*h1.y + W[j].z*h1.z + W[j].w*h1.w; \
    a2 += W[j].x*h2.x + W[j].y*h2.y + W[j].z*h2.z + W[j].w*h2.w; \
    a3 += W[j].x*h3.x + W[j].y*h3.y + W[j].z*h3.z + W[j].w*h3.w; \
  }

// 16 time-batch columns per pass (UB = 0 or 16): caps live a-values at 64 VGPR
// so (16 acc + 40 w + 64 a) fits the 168-VGPR budget of a 640-thread block.
// Round-1 post-mortem: acc[32] batched 128 a-VGPRs -> spill -> 84 GB scratch
// traffic thrashing L2, FETCH 36 GB. Two passes re-stream the 720 KB w_ih
// slice from L2 instead (cheap, amortized over 8 steps).
#define IH_STEP(W, KCB, UB) \
  _Pragma("unroll") \
  for (int j = 0; j < 5; ++j) { \
    const int k4 = ((KCB) + j) * 4; \
    _Pragma("unroll") \
    for (int u = 0; u < 16; ++u) { \
      const float4 a = *(const float4*)&s_Ax[(UB) + u][k4]; \
      acc[u] += W[j].x*a.x + W[j].y*a.y + W[j].z*a.z + W[j].w*a.w; \
    } \
  }

// -----------------------------------------------------------------------------
// Fused BiLSTM, split-pair version.
//  block -> (dir, q, tile): xcd = bi&7: dir=xcd>>2, q=(xcd>>1)&1, so each XCD
//  hosts one (dir,q) combo -> 1.44 MB weight working set per XCD L2.
//  Partner blocks (same dir,tile; q vs 1-q) exchange their 150-unit h slice
//  every step through hxh (parity double-buffered) + monotonic step flags.
//  Exchange uses agent-scope relaxed atomics, no fences (no L2 flush).
// -----------------------------------------------------------------------------
__global__ __launch_bounds__(NTH, 3) void ner_bilstm_kernel(
    const int*    __restrict__ x,
    const float*  __restrict__ emb,
    const float4* __restrict__ wt,       // 4 matrices x 2 slices, k-major
    const float*  __restrict__ bih_f, const float* __restrict__ bhh_f,
    const float*  __restrict__ bih_b, const float* __restrict__ bhh_b,
    const float*  __restrict__ w_proj,   // [9][600]
    float*        __restrict__ em_all,   // 2 dir slabs [S][B][9]
    float*        __restrict__ hxh,      // h exchange: [gid2+q][2][600]
    float*        __restrict__ hxa,      // em-partial exchange: [gid2+q][2][40]
    int*          __restrict__ flags)    // [256] step counters
{
    extern __shared__ float s_pre[];                 // [32][600] = 76.8 KB
    __shared__ float s_Ax[32][304];                  // gathered embeddings
    __shared__ float s_h[TILE_B][304];               // full h_{t-1} (both halves)
    __shared__ float s_c[TILE_B][152];               // own 150 c values
    __shared__ float s_gbuf[TILE_B][ROWS];           // own gate preacts
    __shared__ float s_emp[TILE_B][kT][10];          // emission partial chunks
    __shared__ float s_emf[40], s_emf2[40];          // reduced partials (q0)
    // total LDS ~134 KB -> 1 block/CU.

    const int bi   = blockIdx.x;
    const int xcd  = bi & 7;
    const int dir  = xcd >> 2;
    const int q    = (xcd >> 1) & 1;
    const int tile = (bi >> 3) * 2 + (xcd & 1);      // 0..63
    const int tid  = threadIdx.x;

    const float4* wih4 = wt + ((size_t)(dir * 2 + 0)) * 2 * SLICE_F4 + (size_t)q * SLICE_F4;
    const float4* whh4 = wt + ((size_t)(dir * 2 + 1)) * 2 * SLICE_F4 + (size_t)q * SLICE_F4;
    const float*  bih  = dir ? bih_b : bih_f;
    const float*  bhh  = dir ? bhh_b : bhh_f;
    float* emout = em_all + (size_t)dir * EMSZ;

    const int gid2 = (dir * 64 + tile) * 2;
    float* hx_own  = hxh + (size_t)(gid2 + q)       * 2 * ROWS;
    float* hx_par  = hxh + (size_t)(gid2 + (1 - q)) * 2 * ROWS;
    float* hxa_own = hxa + (size_t)(gid2 + q)       * 2 * 40;
    float* hxa_par = hxa + (size_t)(gid2 + (1 - q)) * 2 * 40;
    int* flag_own  = flags + gid2 + q;
    int* flag_par  = flags + gid2 + (1 - q);

    float bsum = 0.0f;
    if (tid < ROWS) {
        const int gate = tid / 150, ii = tid - gate * 150;
        const int r = gate * 300 + q * 150 + ii;
        bsum = bih[r] + bhh[r];
    }

    for (int i = tid; i < TILE_B * 304; i += NTH) (&s_h[0][0])[i] = 0.0f;
    for (int i = tid; i < TILE_B * 152; i += NTH) (&s_c[0][0])[i] = 0.0f;
    __syncthreads();

    for (int tc = 0; tc < kS / TCHUNK; ++tc) {
        // ---- embedding gather: 32 (tt,b2) rows, 20 lanes each ------------------
        {
            const int rr = tid / 20, ln = tid - rr * 20;
            const int tt = rr >> 2, b2 = rr & 3;
            const int t  = tc * TCHUNK + tt;
            const int s  = dir ? (kS - 1 - t) : t;
            const int token = x[(tile * TILE_B + b2) * kS + s];
            const float* erow = emb + (size_t)token * kE;
            for (int e = ln; e < kE; e += 20) s_Ax[rr][e] = erow[e];
        }
        __syncthreads();

        // ---- input projection, two u-halves to stay spill-free -----------------
        if (tid < ROWS) {
#pragma unroll 1
            for (int half = 0; half < 2; ++half) {
                const int ub = half * 16;
                float acc[16];
#pragma unroll
                for (int u = 0; u < 16; ++u) acc[u] = bsum;
                const float4* wl = wih4 + tid;
                float4 wA[5], wB[5];
                LOAD5(wA);
                int kcb = 0;
                for (int gp = 0; gp < 7; ++gp) {
                    LOAD5(wB);
                    IH_STEP(wA, kcb, ub);
                    kcb += 5;
                    LOAD5(wA);
                    IH_STEP(wB, kcb, ub);
                    kcb += 5;
                }
                IH_STEP(wA, 70, ub);
#pragma unroll
                for (int u = 0; u < 16; ++u) s_pre[(ub + u) * ROWS + tid] = acc[u];
            }
        }
        __syncthreads();

        // ---- recurrent steps ---------------------------------------------------
        for (int tt = 0; tt < TCHUNK; ++tt) {
            const int t   = tc * TCHUNK + tt;
            const int s   = dir ? (kS - 1 - t) : t;
            const int par = t & 1;

            if (tid < ROWS) {
                float a0 = s_pre[(tt * 4 + 0) * ROWS + tid];
                float a1 = s_pre[(tt * 4 + 1) * ROWS + tid];
                float a2 = s_pre[(tt * 4 + 2) * ROWS + tid];
                float a3 = s_pre[(tt * 4 + 3) * ROWS + tid];
                const float4* wl = whh4 + tid;
                float4 wA[5], wB[5];
                LOAD5(wA);
                int kcb = 0;
                for (int gp = 0; gp < 7; ++gp) {
                    LOAD5(wB);
                    HH_STEP(wA, kcb);
                    kcb += 5;
                    LOAD5(wA);
                    HH_STEP(wB, kcb);
                    kcb += 5;
                }
                HH_STEP(wA, 70);
                s_gbuf[0][tid] = a0; s_gbuf[1][tid] = a1;
                s_gbuf[2][tid] = a2; s_gbuf[3][tid] = a3;
            }
            __syncthreads();

            // cell update for own 150 units x 4 batches; store h to exchange buf
            if (tid < ROWS) {
                const int b = tid / 150, i2 = tid - b * 150;
                const float gi = s_gbuf[b][i2];
                const float gf = s_gbuf[b][150 + i2];
                const float gg = s_gbuf[b][300 + i2];
                const float go = s_gbuf[b][450 + i2];
                const float c  = sigmoidf_(gf) * s_c[b][i2] + sigmoidf_(gi) * tanhf(gg);
                const float h  = sigmoidf_(go) * tanhf(c);
                s_c[b][i2] = c;
                s_h[b][q * 150 + i2] = h;
                __hip_atomic_store(&hx_own[par * ROWS + tid], h,
                                   __ATOMIC_RELAXED, __HIP_MEMORY_SCOPE_AGENT);
            }
            __syncthreads();

            // emission partials over own slice
            if (tid < 360) {
                const int b = tid / 90, rem = tid - b * 90;
                const int tag = rem / 10, ch = rem - tag * 10;
                const int n0 = ch * 15;
                const float* wrow = w_proj + tag * (2 * kH) + dir * kH + q * 150 + n0;
                const float* hrow = &s_h[b][q * 150 + n0];
                float sum = 0.0f;
#pragma unroll
                for (int k2 = 0; k2 < 15; ++k2) sum += hrow[k2] * wrow[k2];
                s_emp[b][tag][ch] = sum;
            }
            __syncthreads();
            if (tid < 36) {
                const int b = tid / 9, tag = tid - b * 9;
                float v = 0.0f;
#pragma unroll
                for (int ch = 0; ch < 10; ++ch) v += s_emp[b][tag][ch];
                if (q) __hip_atomic_store(&hxa_own[par * 40 + tid], v,
                                          __ATOMIC_RELAXED, __HIP_MEMORY_SCOPE_AGENT);
                else   s_emf[tid] = v;
            }
            // each wave drains its own agent stores, barrier, then signal
            asm volatile("s_waitcnt vmcnt(0)" ::: "memory");
            __syncthreads();
            if (tid == 0) {
                __hip_atomic_store(flag_own, t + 1,
                                   __ATOMIC_RELAXED, __HIP_MEMORY_SCOPE_AGENT);
                int spins = 0;
                while (__hip_atomic_load(flag_par, __ATOMIC_RELAXED,
                                         __HIP_MEMORY_SCOPE_AGENT) < t + 1) {
                    __builtin_amdgcn_s_sleep(2);
                    if (++spins > (1 << 22)) break;   // hang safety
                }
            }
            __syncthreads();
            // pull partner's h half (+ partner emission partial for q0)
            if (tid < ROWS) {
                const int b = tid / 150, i2 = tid - b * 150;
                s_h[b][(1 - q) * 150 + i2] =
                    __hip_atomic_load(&hx_par[par * ROWS + tid],
                                      __ATOMIC_RELAXED, __HIP_MEMORY_SCOPE_AGENT);
            } else if (!q && tid < ROWS + 36) {
                s_emf2[tid - ROWS] =
                    __hip_atomic_load(&hxa_par[par * 40 + (tid - ROWS)],
                                      __ATOMIC_RELAXED, __HIP_MEMORY_SCOPE_AGENT);
            }
            __syncthreads();
            if (!q && tid < 36) {
                const int b = tid / 9, tag = tid - b * 9;
                emout[((size_t)s * kB + tile * TILE_B + b) * kT + tag] =
                    s_emf[tid] + s_emf2[tid];
            }
            // next phase writes s_gbuf/s_Ax/s_pre, all separated from the reads
            // above by >=2 barriers in the next step
        }
    }
}

// -----------------------------------------------------------------------------
// CRF Viterbi decode (unchanged). 9 lanes per batch row.
// -----------------------------------------------------------------------------
__global__ __launch_bounds__(256) void ner_viterbi_kernel(
    const float* __restrict__ em_all,
    const float* __restrict__ b_proj,
    const float* __restrict__ start_t,
    const float* __restrict__ end_t,
    const float* __restrict__ trans,
    int*         __restrict__ out)
{
    const float* em_f = em_all;
    const float* em_b = em_all + EMSZ;

    __shared__ uint8_t bp[kS - 1][28][kT];

    const int tid  = threadIdx.x;
    const int wave = tid >> 6;
    const int lane = tid & 63;
    const int g    = lane / kT;
    const int nx   = lane % kT;
    const bool active = (g < 7);
    const int gg   = wave * 7 + g;
    const int b    = blockIdx.x * 28 + (active ? gg : 0);
    const bool valid = active && (b < kB);
    const int beff = (b < kB) ? b : (kB - 1);
    const int base = g * kT;

    float tcol[kT];
#pragma unroll
    for (int p = 0; p < kT; ++p) tcol[p] = trans[p * kT + nx];
    const float bpj = b_proj[nx];

    float score = start_t[nx]
                + em_f[(size_t)beff * kT + nx]
                + em_b[(size_t)beff * kT + nx]
                + bpj;

    for (int t = 1; t < kS; ++t) {
        const size_t ei = ((size_t)t * kB + beff) * kT + nx;
        const float em = em_f[ei] + em_b[ei] + bpj;
        float best = -3.402823466e38f;
        int bidx = 0;
#pragma unroll
        for (int p = 0; p < kT; ++p) {
            const float sp = __shfl(score, base + p, 64);
            const float cand = sp + tcol[p];
            if (cand > best) { best = cand; bidx = p; }
        }
        if (valid) bp[t - 1][gg][nx] = (uint8_t)bidx;
        score = best + em;
    }

    score += end_t[nx];
    float best = -3.402823466e38f;
    int last = 0;
#pragma unroll
    for (int p = 0; p < kT; ++p) {
        const float sp = __shfl(score, base + p, 64);
        if (sp > best) { best = sp; last = p; }
    }

    __syncthreads();

    if (valid && nx == 0) {
        int cur = last;
        out[beff * kS + (kS - 1)] = cur;
        for (int t = kS - 2; t >= 0; --t) {
            cur = bp[t][gg][cur];
            out[beff * kS + t] = cur;
        }
    }
}

// -----------------------------------------------------------------------------
extern "C" void kernel_launch(void* const* d_in, const int* in_sizes, int n_in,
                              void* d_out, int out_size, void* d_ws, size_t ws_size,
                              hipStream_t stream) {
    const int*   x       = (const int*)  d_in[0];
    const float* emb     = (const float*)d_in[1];
    const float* w_ih_f  = (const float*)d_in[2];
    const float* w_hh_f  = (const float*)d_in[3];
    const float* b_ih_f  = (const float*)d_in[4];
    const float* b_hh_f  = (const float*)d_in[5];
    const float* w_ih_b  = (const float*)d_in[6];
    const float* w_hh_b  = (const float*)d_in[7];
    const float* b_ih_b  = (const float*)d_in[8];
    const float* b_hh_b  = (const float*)d_in[9];
    const float* w_proj  = (const float*)d_in[10];
    const float* b_proj  = (const float*)d_in[11];
    const float* start_t = (const float*)d_in[12];
    const float* end_t   = (const float*)d_in[13];
    const float* trans   = (const float*)d_in[14];

    // workspace: em (4.72 MB) | wt 4x2 slices (5.76 MB) | hxh (1.23 MB) |
    //            hxa (80 KB) | flags (1 KB)  => ~11.8 MB
    float*  em_all = (float*)d_ws;
    float4* wt     = (float4*)((char*)d_ws + (size_t)2 * EMSZ * 4);
    float*  hxh    = (float*)((char*)wt + (size_t)4 * 2 * SLICE_F4 * sizeof(float4));
    float*  hxa    = hxh + (size_t)256 * 2 * ROWS;
    int*    flags  = (int*)(hxa + (size_t)256 * 2 * 40);

    dim3 tgrid((2 * SLICE_F4 + 255) / 256, 4);
    transpose_w_all<<<tgrid, 256, 0, stream>>>(w_ih_f, w_hh_f, w_ih_b, w_hh_b, wt, flags);

    ner_bilstm_kernel<<<256, NTH, 32 * ROWS * sizeof(float), stream>>>(
        x, emb, wt, b_ih_f, b_hh_f, b_ih_b, b_hh_b, w_proj,
        em_all, hxh, hxa, flags);

    ner_viterbi_kernel<<<10, 256, 0, stream>>>(
        em_all, b_proj, start_t, end_t, trans, (int*)d_out);
}

// Round 3
// 13462.968 us; speedup vs baseline: 1.7685x; 1.0250x over previous
//
#include <hip/hip_runtime.h>
#include <stdint.h>

// Problem constants
#define kS 256      // sequence length
#define kB 256      // batch
#define kE 300      // embedding dim
#define kH 300      // hidden per direction
#define kG 1200     // 4*H gate rows
#define kT 9        // tags

// Decomposition: each (dir, 4-batch tile) is computed by 2 partner blocks,
// each owning 600 gate rows (= 150 hidden units x 4 gates). Per-step h
// exchange between partners via agent-scope atomics (no fences -> L2 weight
// cache stays intact). 256 blocks x 640 threads, 1 block/CU, 10 waves/CU.
#define ROWS 600        // gate rows per block
#define TILE_B 4        // batch rows per group
#define TCHUNK 8        // timesteps per input-projection chunk
#define NTH 640         // threads per block (10 waves)
#define SLICE_F4 45000  // 75 * 600 float4 per weight slice
#define EMSZ (kS * kB * kT)

__device__ __forceinline__ float sigmoidf_(float v) { return 1.0f / (1.0f + expf(-v)); }

// -----------------------------------------------------------------------------
// Pre-pass: transpose [1200][300] weights into per-split k-major float4 layout.
// -----------------------------------------------------------------------------
__global__ __launch_bounds__(256) void transpose_w_all(
    const float* __restrict__ w_ih_f, const float* __restrict__ w_hh_f,
    const float* __restrict__ w_ih_b, const float* __restrict__ w_hh_b,
    float4* __restrict__ wt, int* __restrict__ flags)
{
    const int m = blockIdx.y;  // 0: ih_f, 1: hh_f, 2: ih_b, 3: hh_b
    const float* w = (m == 0) ? w_ih_f : (m == 1) ? w_hh_f : (m == 2) ? w_ih_b : w_hh_b;
    if (blockIdx.y == 0 && blockIdx.x == 0) flags[threadIdx.x] = 0;
    int i = blockIdx.x * 256 + threadIdx.x;
    if (i >= 2 * SLICE_F4) return;
    const int q    = i / SLICE_F4;
    const int rem  = i - q * SLICE_F4;
    const int kc   = rem / ROWS;
    const int rr   = rem - kc * ROWS;
    const int gate = rr / 150;
    const int ii   = rr - gate * 150;
    const int r    = gate * 300 + q * 150 + ii;
    const float* p = w + (size_t)r * 300 + kc * 4;
    wt[(size_t)m * 2 * SLICE_F4 + i] = make_float4(p[0], p[1], p[2], p[3]);
}

// 5-kc group load (prefetch one group ahead of compute)
#define LOAD5(W) { _Pragma("unroll") for (int j = 0; j < 5; ++j) W[j] = wl[j * ROWS]; wl += 5 * ROWS; }

#define HH_STEP(W, KCB) \
  _Pragma("unroll") \
  for (int j = 0; j < 5; ++j) { \
    const int k4 = ((KCB) + j) * 4; \
    const float4 h0 = *(const float4*)&s_h[0][k4]; \
    const float4 h1 = *(const float4*)&s_h[1][k4]; \
    const float4 h2 = *(const float4*)&s_h[2][k4]; \
    const float4 h3 = *(const float4*)&s_h[3][k4]; \
    a0 += W[j].x*h0.x + W[j].y*h0.y + W[j].z*h0.z + W[j].w*h0.w; \
    a1 += W[j].x*h1.x + W[j].y*h1.y + W[j].z*h1.z + W[j].w*h1.w; \
    a2 += W[j].x*h2.x + W[j].y*h2.y + W[j].z*h2.z + W[j].w*h2.w; \
    a3 += W[j].x*h3.x + W[j].y*h3.y + W[j].z*h3.z + W[j].w*h3.w; \
  }

// 16 time-batch columns per pass (UB = 0 or 16): caps live a-values at 64 VGPR
// so (16 acc + 40 w + 64 a) fits the ~170-VGPR budget of a 640-thread block.
#define IH_STEP(W, KCB, UB) \
  _Pragma("unroll") \
  for (int j = 0; j < 5; ++j) { \
    const int k4 = ((KCB) + j) * 4; \
    _Pragma("unroll") \
    for (int u = 0; u < 16; ++u) { \
      const float4 a = *(const float4*)&s_Ax[(UB) + u][k4]; \
      acc[u] += W[j].x*a.x + W[j].y*a.y + W[j].z*a.z + W[j].w*a.w; \
    } \
  }

// -----------------------------------------------------------------------------
// Fused BiLSTM, split-pair version.
//  block -> (dir, q, tile): xcd = bi&7: dir=xcd>>2, q=(xcd>>1)&1, so each XCD
//  hosts one (dir,q) combo -> 1.44 MB weight working set per XCD L2.
//  Partner blocks (same dir,tile; q vs 1-q) exchange their 150-unit h slice
//  every step through hxh (parity double-buffered) + monotonic step flags.
//  Exchange uses agent-scope relaxed atomics, no fences (no L2 flush).
//
//  R1/R2 post-mortem: __launch_bounds__(640, 3) made the compiler cap VGPRs at
//  84 (6 waves/EU budget) -> ~50 regs spilled to scratch -> 22-46 GB of HBM
//  scratch traffic thrashing L2. With no min-waves hint, flat_work_group_size
//  = 640 alone caps VGPRs at 512/3 = 170 (a 10-wave block puts 3 waves on one
//  SIMD), which both GEMM phases were sized to fit spill-free. Occupancy stays
//  1 block/CU (LDS-bound) either way.
// -----------------------------------------------------------------------------
__global__ __launch_bounds__(NTH) void ner_bilstm_kernel(
    const int*    __restrict__ x,
    const float*  __restrict__ emb,
    const float4* __restrict__ wt,       // 4 matrices x 2 slices, k-major
    const float*  __restrict__ bih_f, const float* __restrict__ bhh_f,
    const float*  __restrict__ bih_b, const float* __restrict__ bhh_b,
    const float*  __restrict__ w_proj,   // [9][600]
    float*        __restrict__ em_all,   // 2 dir slabs [S][B][9]
    float*        __restrict__ hxh,      // h exchange: [gid2+q][2][600]
    float*        __restrict__ hxa,      // em-partial exchange: [gid2+q][2][40]
    int*          __restrict__ flags)    // [256] step counters
{
    extern __shared__ float s_pre[];                 // [32][600] = 76.8 KB
    __shared__ float s_Ax[32][304];                  // gathered embeddings
    __shared__ float s_h[TILE_B][304];               // full h_{t-1} (both halves)
    __shared__ float s_c[TILE_B][152];               // own 150 c values
    __shared__ float s_gbuf[TILE_B][ROWS];           // own gate preacts
    __shared__ float s_emp[TILE_B][kT][10];          // emission partial chunks
    __shared__ float s_emf[40], s_emf2[40];          // reduced partials (q0)
    // total LDS ~134 KB -> 1 block/CU.

    const int bi   = blockIdx.x;
    const int xcd  = bi & 7;
    const int dir  = xcd >> 2;
    const int q    = (xcd >> 1) & 1;
    const int tile = (bi >> 3) * 2 + (xcd & 1);      // 0..63
    const int tid  = threadIdx.x;

    const float4* wih4 = wt + ((size_t)(dir * 2 + 0)) * 2 * SLICE_F4 + (size_t)q * SLICE_F4;
    const float4* whh4 = wt + ((size_t)(dir * 2 + 1)) * 2 * SLICE_F4 + (size_t)q * SLICE_F4;
    const float*  bih  = dir ? bih_b : bih_f;
    const float*  bhh  = dir ? bhh_b : bhh_f;
    float* emout = em_all + (size_t)dir * EMSZ;

    const int gid2 = (dir * 64 + tile) * 2;
    float* hx_own  = hxh + (size_t)(gid2 + q)       * 2 * ROWS;
    float* hx_par  = hxh + (size_t)(gid2 + (1 - q)) * 2 * ROWS;
    float* hxa_own = hxa + (size_t)(gid2 + q)       * 2 * 40;
    float* hxa_par = hxa + (size_t)(gid2 + (1 - q)) * 2 * 40;
    int* flag_own  = flags + gid2 + q;
    int* flag_par  = flags + gid2 + (1 - q);

    float bsum = 0.0f;
    if (tid < ROWS) {
        const int gate = tid / 150, ii = tid - gate * 150;
        const int r = gate * 300 + q * 150 + ii;
        bsum = bih[r] + bhh[r];
    }

    for (int i = tid; i < TILE_B * 304; i += NTH) (&s_h[0][0])[i] = 0.0f;
    for (int i = tid; i < TILE_B * 152; i += NTH) (&s_c[0][0])[i] = 0.0f;
    __syncthreads();

    for (int tc = 0; tc < kS / TCHUNK; ++tc) {
        // ---- embedding gather: 32 (tt,b2) rows, 20 lanes each ------------------
        {
            const int rr = tid / 20, ln = tid - rr * 20;
            const int tt = rr >> 2, b2 = rr & 3;
            const int t  = tc * TCHUNK + tt;
            const int s  = dir ? (kS - 1 - t) : t;
            const int token = x[(tile * TILE_B + b2) * kS + s];
            const float* erow = emb + (size_t)token * kE;
            for (int e = ln; e < kE; e += 20) s_Ax[rr][e] = erow[e];
        }
        __syncthreads();

        // ---- input projection, two u-halves to stay spill-free -----------------
        if (tid < ROWS) {
#pragma unroll 1
            for (int half = 0; half < 2; ++half) {
                const int ub = half * 16;
                float acc[16];
#pragma unroll
                for (int u = 0; u < 16; ++u) acc[u] = bsum;
                const float4* wl = wih4 + tid;
                float4 wA[5], wB[5];
                LOAD5(wA);
                int kcb = 0;
                for (int gp = 0; gp < 7; ++gp) {
                    LOAD5(wB);
                    IH_STEP(wA, kcb, ub);
                    kcb += 5;
                    LOAD5(wA);
                    IH_STEP(wB, kcb, ub);
                    kcb += 5;
                }
                IH_STEP(wA, 70, ub);
#pragma unroll
                for (int u = 0; u < 16; ++u) s_pre[(ub + u) * ROWS + tid] = acc[u];
            }
        }
        __syncthreads();

        // ---- recurrent steps ---------------------------------------------------
        for (int tt = 0; tt < TCHUNK; ++tt) {
            const int t   = tc * TCHUNK + tt;
            const int s   = dir ? (kS - 1 - t) : t;
            const int par = t & 1;

            if (tid < ROWS) {
                float a0 = s_pre[(tt * 4 + 0) * ROWS + tid];
                float a1 = s_pre[(tt * 4 + 1) * ROWS + tid];
                float a2 = s_pre[(tt * 4 + 2) * ROWS + tid];
                float a3 = s_pre[(tt * 4 + 3) * ROWS + tid];
                const float4* wl = whh4 + tid;
                float4 wA[5], wB[5];
                LOAD5(wA);
                int kcb = 0;
                for (int gp = 0; gp < 7; ++gp) {
                    LOAD5(wB);
                    HH_STEP(wA, kcb);
                    kcb += 5;
                    LOAD5(wA);
                    HH_STEP(wB, kcb);
                    kcb += 5;
                }
                HH_STEP(wA, 70);
                s_gbuf[0][tid] = a0; s_gbuf[1][tid] = a1;
                s_gbuf[2][tid] = a2; s_gbuf[3][tid] = a3;
            }
            __syncthreads();

            // cell update for own 150 units x 4 batches; store h to exchange buf
            if (tid < ROWS) {
                const int b = tid / 150, i2 = tid - b * 150;
                const float gi = s_gbuf[b][i2];
                const float gf = s_gbuf[b][150 + i2];
                const float gg = s_gbuf[b][300 + i2];
                const float go = s_gbuf[b][450 + i2];
                const float c  = sigmoidf_(gf) * s_c[b][i2] + sigmoidf_(gi) * tanhf(gg);
                const float h  = sigmoidf_(go) * tanhf(c);
                s_c[b][i2] = c;
                s_h[b][q * 150 + i2] = h;
                __hip_atomic_store(&hx_own[par * ROWS + tid], h,
                                   __ATOMIC_RELAXED, __HIP_MEMORY_SCOPE_AGENT);
            }
            __syncthreads();

            // emission partials over own slice
            if (tid < 360) {
                const int b = tid / 90, rem = tid - b * 90;
                const int tag = rem / 10, ch = rem - tag * 10;
                const int n0 = ch * 15;
                const float* wrow = w_proj + tag * (2 * kH) + dir * kH + q * 150 + n0;
                const float* hrow = &s_h[b][q * 150 + n0];
                float sum = 0.0f;
#pragma unroll
                for (int k2 = 0; k2 < 15; ++k2) sum += hrow[k2] * wrow[k2];
                s_emp[b][tag][ch] = sum;
            }
            __syncthreads();
            if (tid < 36) {
                const int b = tid / 9, tag = tid - b * 9;
                float v = 0.0f;
#pragma unroll
                for (int ch = 0; ch < 10; ++ch) v += s_emp[b][tag][ch];
                if (q) __hip_atomic_store(&hxa_own[par * 40 + tid], v,
                                          __ATOMIC_RELAXED, __HIP_MEMORY_SCOPE_AGENT);
                else   s_emf[tid] = v;
            }
            // each wave drains its own agent stores, barrier, then signal
            asm volatile("s_waitcnt vmcnt(0)" ::: "memory");
            __syncthreads();
            if (tid == 0) {
                __hip_atomic_store(flag_own, t + 1,
                                   __ATOMIC_RELAXED, __HIP_MEMORY_SCOPE_AGENT);
                int spins = 0;
                while (__hip_atomic_load(flag_par, __ATOMIC_RELAXED,
                                         __HIP_MEMORY_SCOPE_AGENT) < t + 1) {
                    __builtin_amdgcn_s_sleep(2);
                    if (++spins > (1 << 22)) break;   // hang safety
                }
            }
            __syncthreads();
            // pull partner's h half (+ partner emission partial for q0)
            if (tid < ROWS) {
                const int b = tid / 150, i2 = tid - b * 150;
                s_h[b][(1 - q) * 150 + i2] =
                    __hip_atomic_load(&hx_par[par * ROWS + tid],
                                      __ATOMIC_RELAXED, __HIP_MEMORY_SCOPE_AGENT);
            } else if (!q && tid < ROWS + 36) {
                s_emf2[tid - ROWS] =
                    __hip_atomic_load(&hxa_par[par * 40 + (tid - ROWS)],
                                      __ATOMIC_RELAXED, __HIP_MEMORY_SCOPE_AGENT);
            }
            __syncthreads();
            if (!q && tid < 36) {
                const int b = tid / 9, tag = tid - b * 9;
                emout[((size_t)s * kB + tile * TILE_B + b) * kT + tag] =
                    s_emf[tid] + s_emf2[tid];
            }
            // next phase writes s_gbuf/s_Ax/s_pre, all separated from the reads
            // above by >=2 barriers in the next step
        }
    }
}

// -----------------------------------------------------------------------------
// CRF Viterbi decode (unchanged). 9 lanes per batch row.
// -----------------------------------------------------------------------------
__global__ __launch_bounds__(256) void ner_viterbi_kernel(
    const float* __restrict__ em_all,
    const float* __restrict__ b_proj,
    const float* __restrict__ start_t,
    const float* __restrict__ end_t,
    const float* __restrict__ trans,
    int*         __restrict__ out)
{
    const float* em_f = em_all;
    const float* em_b = em_all + EMSZ;

    __shared__ uint8_t bp[kS - 1][28][kT];

    const int tid  = threadIdx.x;
    const int wave = tid >> 6;
    const int lane = tid & 63;
    const int g    = lane / kT;
    const int nx   = lane % kT;
    const bool active = (g < 7);
    const int gg   = wave * 7 + g;
    const int b    = blockIdx.x * 28 + (active ? gg : 0);
    const bool valid = active && (b < kB);
    const int beff = (b < kB) ? b : (kB - 1);
    const int base = g * kT;

    float tcol[kT];
#pragma unroll
    for (int p = 0; p < kT; ++p) tcol[p] = trans[p * kT + nx];
    const float bpj = b_proj[nx];

    float score = start_t[nx]
                + em_f[(size_t)beff * kT + nx]
                + em_b[(size_t)beff * kT + nx]
                + bpj;

    for (int t = 1; t < kS; ++t) {
        const size_t ei = ((size_t)t * kB + beff) * kT + nx;
        const float em = em_f[ei] + em_b[ei] + bpj;
        float best = -3.402823466e38f;
        int bidx = 0;
#pragma unroll
        for (int p = 0; p < kT; ++p) {
            const float sp = __shfl(score, base + p, 64);
            const float cand = sp + tcol[p];
            if (cand > best) { best = cand; bidx = p; }
        }
        if (valid) bp[t - 1][gg][nx] = (uint8_t)bidx;
        score = best + em;
    }

    score += end_t[nx];
    float best = -3.402823466e38f;
    int last = 0;
#pragma unroll
    for (int p = 0; p < kT; ++p) {
        const float sp = __shfl(score, base + p, 64);
        if (sp > best) { best = sp; last = p; }
    }

    __syncthreads();

    if (valid && nx == 0) {
        int cur = last;
        out[beff * kS + (kS - 1)] = cur;
        for (int t = kS - 2; t >= 0; --t) {
            cur = bp[t][gg][cur];
            out[beff * kS + t] = cur;
        }
    }
}

// -----------------------------------------------------------------------------
extern "C" void kernel_launch(void* const* d_in, const int* in_sizes, int n_in,
                              void* d_out, int out_size, void* d_ws, size_t ws_size,
                              hipStream_t stream) {
    const int*   x       = (const int*)  d_in[0];
    const float* emb     = (const float*)d_in[1];
    const float* w_ih_f  = (const float*)d_in[2];
    const float* w_hh_f  = (const float*)d_in[3];
    const float* b_ih_f  = (const float*)d_in[4];
    const float* b_hh_f  = (const float*)d_in[5];
    const float* w_ih_b  = (const float*)d_in[6];
    const float* w_hh_b  = (const float*)d_in[7];
    const float* b_ih_b  = (const float*)d_in[8];
    const float* b_hh_b  = (const float*)d_in[9];
    const float* w_proj  = (const float*)d_in[10];
    const float* b_proj  = (const float*)d_in[11];
    const float* start_t = (const float*)d_in[12];
    const float* end_t   = (const float*)d_in[13];
    const float* trans   = (const float*)d_in[14];

    // workspace: em (4.72 MB) | wt 4x2 slices (5.76 MB) | hxh (1.23 MB) |
    //            hxa (80 KB) | flags (1 KB)  => ~11.8 MB
    float*  em_all = (float*)d_ws;
    float4* wt     = (float4*)((char*)d_ws + (size_t)2 * EMSZ * 4);
    float*  hxh    = (float*)((char*)wt + (size_t)4 * 2 * SLICE_F4 * sizeof(float4));
    float*  hxa    = hxh + (size_t)256 * 2 * ROWS;
    int*    flags  = (int*)(hxa + (size_t)256 * 2 * 40);

    dim3 tgrid((2 * SLICE_F4 + 255) / 256, 4);
    transpose_w_all<<<tgrid, 256, 0, stream>>>(w_ih_f, w_hh_f, w_ih_b, w_hh_b, wt, flags);

    ner_bilstm_kernel<<<256, NTH, 32 * ROWS * sizeof(float), stream>>>(
        x, emb, wt, b_ih_f, b_hh_f, b_ih_b, b_hh_b, w_proj,
        em_all, hxh, hxa, flags);

    ner_viterbi_kernel<<<10, 256, 0, stream>>>(
        em_all, b_proj, start_t, end_t, trans, (int*)d_out);
}

// Round 4
// 6781.621 us; speedup vs baseline: 3.5109x; 1.9852x over previous
//
#include <hip/hip_runtime.h>
#include <stdint.h>

// Problem constants
#define kS 256      // sequence length
#define kB 256      // batch
#define kE 300      // embedding dim
#define kH 300      // hidden per direction
#define kG 1200     // 4*H gate rows
#define kT 9        // tags

// Decomposition: each (dir, 4-batch tile) is computed by 2 partner blocks,
// each owning 600 gate rows (= 150 hidden units x 4 gates). Per-step h
// exchange between partners via agent-scope atomics (no fences -> L2 weight
// cache stays intact). 256 blocks x 640 threads, 1 block/CU, 10 waves/CU.
//
// R1-R3 post-mortem: the register allocator pins this kernel at 84 VGPRs
// (6 waves/EU target) regardless of launch-bounds/waves-per-eu hints. The
// old 5-row/16-col GEMM phases需要 ~135+ live VGPRs (compiler batches the
// per-group LDS a-loads), so they memory-spilled ~45 GB of scratch traffic
// per dispatch, thrashing L2 (FETCH 22 GB, WRITE 24 GB). Fix: restructure
// both GEMM phases to a 1-row-per-thread shape whose peak live set (~40-55
// VGPRs) fits INSIDE 84 with margin. #pragma unroll 1 on kc loops prevents
// cross-iteration load batching from re-inflating pressure.
#define ROWS 600        // gate rows per block
#define TILE_B 4        // batch rows per group
#define TCHUNK 8        // timesteps per input-projection chunk
#define NTH 640         // threads per block (10 waves)
#define SLICE_F4 45000  // 75 * 600 float4 per weight slice
#define EMSZ (kS * kB * kT)

__device__ __forceinline__ float sigmoidf_(float v) { return 1.0f / (1.0f + expf(-v)); }

// -----------------------------------------------------------------------------
// Pre-pass: transpose [1200][300] weights into per-split k-major float4 layout.
// wt[m][q][kc][rr]: consecutive rr (= consecutive tid) read consecutive 16B.
// -----------------------------------------------------------------------------
__global__ __launch_bounds__(256) void transpose_w_all(
    const float* __restrict__ w_ih_f, const float* __restrict__ w_hh_f,
    const float* __restrict__ w_ih_b, const float* __restrict__ w_hh_b,
    float4* __restrict__ wt, int* __restrict__ flags)
{
    const int m = blockIdx.y;  // 0: ih_f, 1: hh_f, 2: ih_b, 3: hh_b
    const float* w = (m == 0) ? w_ih_f : (m == 1) ? w_hh_f : (m == 2) ? w_ih_b : w_hh_b;
    if (blockIdx.y == 0 && blockIdx.x == 0) flags[threadIdx.x] = 0;
    int i = blockIdx.x * 256 + threadIdx.x;
    if (i >= 2 * SLICE_F4) return;
    const int q    = i / SLICE_F4;
    const int rem  = i - q * SLICE_F4;
    const int kc   = rem / ROWS;
    const int rr   = rem - kc * ROWS;
    const int gate = rr / 150;
    const int ii   = rr - gate * 150;
    const int r    = gate * 300 + q * 150 + ii;
    const float* p = w + (size_t)r * 300 + kc * 4;
    wt[(size_t)m * 2 * SLICE_F4 + i] = make_float4(p[0], p[1], p[2], p[3]);
}

// -----------------------------------------------------------------------------
// Fused BiLSTM, split-pair version.
//  block -> (dir, q, tile): xcd = bi&7: dir=xcd>>2, q=(xcd>>1)&1, so each XCD
//  hosts one (dir,q) combo -> 1.44 MB weight working set per XCD L2.
//  Partner blocks (same dir,tile; q vs 1-q) exchange their 150-unit h slice
//  every step through hxh (parity double-buffered) + monotonic step flags.
//  Exchange uses agent-scope relaxed atomics, no fences (no L2 flush).
// -----------------------------------------------------------------------------
__global__ __launch_bounds__(NTH) void ner_bilstm_kernel(
    const int*    __restrict__ x,
    const float*  __restrict__ emb,
    const float4* __restrict__ wt,       // 4 matrices x 2 slices, k-major
    const float*  __restrict__ bih_f, const float* __restrict__ bhh_f,
    const float*  __restrict__ bih_b, const float* __restrict__ bhh_b,
    const float*  __restrict__ w_proj,   // [9][600]
    float*        __restrict__ em_all,   // 2 dir slabs [S][B][9]
    float*        __restrict__ hxh,      // h exchange: [gid2+q][2][600]
    float*        __restrict__ hxa,      // em-partial exchange: [gid2+q][2][40]
    int*          __restrict__ flags)    // [256] step counters
{
    extern __shared__ float s_pre[];                 // [32][600] = 76.8 KB
    __shared__ float s_Ax[32][304];                  // gathered embeddings
    __shared__ float s_h[TILE_B][304];               // full h_{t-1} (both halves)
    __shared__ float s_c[TILE_B][152];               // own 150 c values
    __shared__ float s_gbuf[TILE_B][ROWS];           // own gate preacts
    __shared__ float s_emp[TILE_B][kT][10];          // emission partial chunks
    __shared__ float s_emf[40], s_emf2[40];          // reduced partials (q0)
    // total LDS ~134 KB -> 1 block/CU.

    const int bi   = blockIdx.x;
    const int xcd  = bi & 7;
    const int dir  = xcd >> 2;
    const int q    = (xcd >> 1) & 1;
    const int tile = (bi >> 3) * 2 + (xcd & 1);      // 0..63
    const int tid  = threadIdx.x;

    const float4* wih4 = wt + ((size_t)(dir * 2 + 0)) * 2 * SLICE_F4 + (size_t)q * SLICE_F4;
    const float4* whh4 = wt + ((size_t)(dir * 2 + 1)) * 2 * SLICE_F4 + (size_t)q * SLICE_F4;
    const float*  bih  = dir ? bih_b : bih_f;
    const float*  bhh  = dir ? bhh_b : bhh_f;
    float* emout = em_all + (size_t)dir * EMSZ;

    const int gid2 = (dir * 64 + tile) * 2;
    float* hx_own  = hxh + (size_t)(gid2 + q)       * 2 * ROWS;
    float* hx_par  = hxh + (size_t)(gid2 + (1 - q)) * 2 * ROWS;
    float* hxa_own = hxa + (size_t)(gid2 + q)       * 2 * 40;
    float* hxa_par = hxa + (size_t)(gid2 + (1 - q)) * 2 * 40;
    int* flag_own  = flags + gid2 + q;
    int* flag_par  = flags + gid2 + (1 - q);

    float bsum = 0.0f;
    if (tid < ROWS) {
        const int gate = tid / 150, ii = tid - gate * 150;
        const int r = gate * 300 + q * 150 + ii;
        bsum = bih[r] + bhh[r];
    }

    for (int i = tid; i < TILE_B * 304; i += NTH) (&s_h[0][0])[i] = 0.0f;
    for (int i = tid; i < TILE_B * 152; i += NTH) (&s_c[0][0])[i] = 0.0f;
    __syncthreads();

    for (int tc = 0; tc < kS / TCHUNK; ++tc) {
        // ---- embedding gather: 32 (tt,b2) rows, 20 lanes each ------------------
        {
            const int rr = tid / 20, ln = tid - rr * 20;
            const int tt = rr >> 2, b2 = rr & 3;
            const int t  = tc * TCHUNK + tt;
            const int s  = dir ? (kS - 1 - t) : t;
            const int token = x[(tile * TILE_B + b2) * kS + s];
            const float* erow = emb + (size_t)token * kE;
            for (int e = ln; e < kE; e += 20) s_Ax[rr][e] = erow[e];
        }
        __syncthreads();

        // ---- input projection: 4 passes of 8 time-batch columns ----------------
        // Per kc: 1 coalesced w float4 (dbuf) + 8 LDS broadcasts + 32 FMA.
        // Peak live ~55 VGPR -> spill-free at the allocator's 84 budget.
        if (tid < ROWS) {
#pragma unroll 1
            for (int half = 0; half < 4; ++half) {
                const int ub = half * 8;
                float acc[8];
#pragma unroll
                for (int u = 0; u < 8; ++u) acc[u] = bsum;
                const float4* wl = wih4 + tid;
                float4 wc = *wl; wl += ROWS;
#pragma unroll 1
                for (int kc = 0; kc < 74; ++kc) {
                    const float4 wn = *wl; wl += ROWS;
                    const int k4 = kc * 4;
#pragma unroll
                    for (int u = 0; u < 8; ++u) {
                        const float4 a = *(const float4*)&s_Ax[ub + u][k4];
                        acc[u] += wc.x*a.x + wc.y*a.y + wc.z*a.z + wc.w*a.w;
                    }
                    wc = wn;
                }
#pragma unroll
                for (int u = 0; u < 8; ++u) {
                    const float4 a = *(const float4*)&s_Ax[ub + u][74 * 4];
                    acc[u] += wc.x*a.x + wc.y*a.y + wc.z*a.z + wc.w*a.w;
                }
#pragma unroll
                for (int u = 0; u < 8; ++u) s_pre[(ub + u) * ROWS + tid] = acc[u];
            }
        }
        __syncthreads();

        // ---- recurrent steps ---------------------------------------------------
        for (int tt = 0; tt < TCHUNK; ++tt) {
            const int t   = tc * TCHUNK + tt;
            const int s   = dir ? (kS - 1 - t) : t;
            const int par = t & 1;

            // gates = pre + h_{t-1} @ w_hh_slice^T
            // Per kc: 1 coalesced w float4 (dbuf) + 4 LDS broadcasts + 16 FMA.
            // Peak live ~40 VGPR.
            if (tid < ROWS) {
                float a0 = s_pre[(tt * 4 + 0) * ROWS + tid];
                float a1 = s_pre[(tt * 4 + 1) * ROWS + tid];
                float a2 = s_pre[(tt * 4 + 2) * ROWS + tid];
                float a3 = s_pre[(tt * 4 + 3) * ROWS + tid];
                const float4* wl = whh4 + tid;
                float4 wc = *wl; wl += ROWS;
#pragma unroll 2
                for (int kc = 0; kc < 74; ++kc) {
                    const float4 wn = *wl; wl += ROWS;
                    const int k4 = kc * 4;
                    const float4 h0 = *(const float4*)&s_h[0][k4];
                    const float4 h1 = *(const float4*)&s_h[1][k4];
                    const float4 h2 = *(const float4*)&s_h[2][k4];
                    const float4 h3 = *(const float4*)&s_h[3][k4];
                    a0 += wc.x*h0.x + wc.y*h0.y + wc.z*h0.z + wc.w*h0.w;
                    a1 += wc.x*h1.x + wc.y*h1.y + wc.z*h1.z + wc.w*h1.w;
                    a2 += wc.x*h2.x + wc.y*h2.y + wc.z*h2.z + wc.w*h2.w;
                    a3 += wc.x*h3.x + wc.y*h3.y + wc.z*h3.z + wc.w*h3.w;
                    wc = wn;
                }
                {   // kc = 74 tail
                    const int k4 = 74 * 4;
                    const float4 h0 = *(const float4*)&s_h[0][k4];
                    const float4 h1 = *(const float4*)&s_h[1][k4];
                    const float4 h2 = *(const float4*)&s_h[2][k4];
                    const float4 h3 = *(const float4*)&s_h[3][k4];
                    a0 += wc.x*h0.x + wc.y*h0.y + wc.z*h0.z + wc.w*h0.w;
                    a1 += wc.x*h1.x + wc.y*h1.y + wc.z*h1.z + wc.w*h1.w;
                    a2 += wc.x*h2.x + wc.y*h2.y + wc.z*h2.z + wc.w*h2.w;
                    a3 += wc.x*h3.x + wc.y*h3.y + wc.z*h3.z + wc.w*h3.w;
                }
                s_gbuf[0][tid] = a0; s_gbuf[1][tid] = a1;
                s_gbuf[2][tid] = a2; s_gbuf[3][tid] = a3;
            }
            __syncthreads();

            // cell update for own 150 units x 4 batches; store h to exchange buf
            if (tid < ROWS) {
                const int b = tid / 150, i2 = tid - b * 150;
                const float gi = s_gbuf[b][i2];
                const float gf = s_gbuf[b][150 + i2];
                const float gg = s_gbuf[b][300 + i2];
                const float go = s_gbuf[b][450 + i2];
                const float c  = sigmoidf_(gf) * s_c[b][i2] + sigmoidf_(gi) * tanhf(gg);
                const float h  = sigmoidf_(go) * tanhf(c);
                s_c[b][i2] = c;
                s_h[b][q * 150 + i2] = h;
                __hip_atomic_store(&hx_own[par * ROWS + tid], h,
                                   __ATOMIC_RELAXED, __HIP_MEMORY_SCOPE_AGENT);
            }
            __syncthreads();

            // emission partials over own slice
            if (tid < 360) {
                const int b = tid / 90, rem = tid - b * 90;
                const int tag = rem / 10, ch = rem - tag * 10;
                const int n0 = ch * 15;
                const float* wrow = w_proj + tag * (2 * kH) + dir * kH + q * 150 + n0;
                const float* hrow = &s_h[b][q * 150 + n0];
                float sum = 0.0f;
#pragma unroll
                for (int k2 = 0; k2 < 15; ++k2) sum += hrow[k2] * wrow[k2];
                s_emp[b][tag][ch] = sum;
            }
            __syncthreads();
            if (tid < 36) {
                const int b = tid / 9, tag = tid - b * 9;
                float v = 0.0f;
#pragma unroll
                for (int ch = 0; ch < 10; ++ch) v += s_emp[b][tag][ch];
                if (q) __hip_atomic_store(&hxa_own[par * 40 + tid], v,
                                          __ATOMIC_RELAXED, __HIP_MEMORY_SCOPE_AGENT);
                else   s_emf[tid] = v;
            }
            // each wave drains its own agent stores, barrier, then signal
            asm volatile("s_waitcnt vmcnt(0)" ::: "memory");
            __syncthreads();
            if (tid == 0) {
                __hip_atomic_store(flag_own, t + 1,
                                   __ATOMIC_RELAXED, __HIP_MEMORY_SCOPE_AGENT);
                int spins = 0;
                while (__hip_atomic_load(flag_par, __ATOMIC_RELAXED,
                                         __HIP_MEMORY_SCOPE_AGENT) < t + 1) {
                    __builtin_amdgcn_s_sleep(2);
                    if (++spins > (1 << 22)) break;   // hang safety
                }
            }
            __syncthreads();
            // pull partner's h half (+ partner emission partial for q0)
            if (tid < ROWS) {
                const int b = tid / 150, i2 = tid - b * 150;
                s_h[b][(1 - q) * 150 + i2] =
                    __hip_atomic_load(&hx_par[par * ROWS + tid],
                                      __ATOMIC_RELAXED, __HIP_MEMORY_SCOPE_AGENT);
            } else if (!q && tid < ROWS + 36) {
                s_emf2[tid - ROWS] =
                    __hip_atomic_load(&hxa_par[par * 40 + (tid - ROWS)],
                                      __ATOMIC_RELAXED, __HIP_MEMORY_SCOPE_AGENT);
            }
            __syncthreads();
            if (!q && tid < 36) {
                const int b = tid / 9, tag = tid - b * 9;
                emout[((size_t)s * kB + tile * TILE_B + b) * kT + tag] =
                    s_emf[tid] + s_emf2[tid];
            }
            // next phase writes s_gbuf/s_Ax/s_pre, all separated from the reads
            // above by >=2 barriers in the next step
        }
    }
}

// -----------------------------------------------------------------------------
// CRF Viterbi decode (unchanged). 9 lanes per batch row.
// -----------------------------------------------------------------------------
__global__ __launch_bounds__(256) void ner_viterbi_kernel(
    const float* __restrict__ em_all,
    const float* __restrict__ b_proj,
    const float* __restrict__ start_t,
    const float* __restrict__ end_t,
    const float* __restrict__ trans,
    int*         __restrict__ out)
{
    const float* em_f = em_all;
    const float* em_b = em_all + EMSZ;

    __shared__ uint8_t bp[kS - 1][28][kT];

    const int tid  = threadIdx.x;
    const int wave = tid >> 6;
    const int lane = tid & 63;
    const int g    = lane / kT;
    const int nx   = lane % kT;
    const bool active = (g < 7);
    const int gg   = wave * 7 + g;
    const int b    = blockIdx.x * 28 + (active ? gg : 0);
    const bool valid = active && (b < kB);
    const int beff = (b < kB) ? b : (kB - 1);
    const int base = g * kT;

    float tcol[kT];
#pragma unroll
    for (int p = 0; p < kT; ++p) tcol[p] = trans[p * kT + nx];
    const float bpj = b_proj[nx];

    float score = start_t[nx]
                + em_f[(size_t)beff * kT + nx]
                + em_b[(size_t)beff * kT + nx]
                + bpj;

    for (int t = 1; t < kS; ++t) {
        const size_t ei = ((size_t)t * kB + beff) * kT + nx;
        const float em = em_f[ei] + em_b[ei] + bpj;
        float best = -3.402823466e38f;
        int bidx = 0;
#pragma unroll
        for (int p = 0; p < kT; ++p) {
            const float sp = __shfl(score, base + p, 64);
            const float cand = sp + tcol[p];
            if (cand > best) { best = cand; bidx = p; }
        }
        if (valid) bp[t - 1][gg][nx] = (uint8_t)bidx;
        score = best + em;
    }

    score += end_t[nx];
    float best = -3.402823466e38f;
    int last = 0;
#pragma unroll
    for (int p = 0; p < kT; ++p) {
        const float sp = __shfl(score, base + p, 64);
        if (sp > best) { best = sp; last = p; }
    }

    __syncthreads();

    if (valid && nx == 0) {
        int cur = last;
        out[beff * kS + (kS - 1)] = cur;
        for (int t = kS - 2; t >= 0; --t) {
            cur = bp[t][gg][cur];
            out[beff * kS + t] = cur;
        }
    }
}

// -----------------------------------------------------------------------------
extern "C" void kernel_launch(void* const* d_in, const int* in_sizes, int n_in,
                              void* d_out, int out_size, void* d_ws, size_t ws_size,
                              hipStream_t stream) {
    const int*   x       = (const int*)  d_in[0];
    const float* emb     = (const float*)d_in[1];
    const float* w_ih_f  = (const float*)d_in[2];
    const float* w_hh_f  = (const float*)d_in[3];
    const float* b_ih_f  = (const float*)d_in[4];
    const float* b_hh_f  = (const float*)d_in[5];
    const float* w_ih_b  = (const float*)d_in[6];
    const float* w_hh_b  = (const float*)d_in[7];
    const float* b_ih_b  = (const float*)d_in[8];
    const float* b_hh_b  = (const float*)d_in[9];
    const float* w_proj  = (const float*)d_in[10];
    const float* b_proj  = (const float*)d_in[11];
    const float* start_t = (const float*)d_in[12];
    const float* end_t   = (const float*)d_in[13];
    const float* trans   = (const float*)d_in[14];

    // workspace: em (4.72 MB) | wt 4x2 slices (5.76 MB) | hxh (1.23 MB) |
    //            hxa (80 KB) | flags (1 KB)  => ~11.8 MB
    float*  em_all = (float*)d_ws;
    float4* wt     = (float4*)((char*)d_ws + (size_t)2 * EMSZ * 4);
    float*  hxh    = (float*)((char*)wt + (size_t)4 * 2 * SLICE_F4 * sizeof(float4));
    float*  hxa    = hxh + (size_t)256 * 2 * ROWS;
    int*    flags  = (int*)(hxa + (size_t)256 * 2 * 40);

    dim3 tgrid((2 * SLICE_F4 + 255) / 256, 4);
    transpose_w_all<<<tgrid, 256, 0, stream>>>(w_ih_f, w_hh_f, w_ih_b, w_hh_b, wt, flags);

    ner_bilstm_kernel<<<256, NTH, 32 * ROWS * sizeof(float), stream>>>(
        x, emb, wt, b_ih_f, b_hh_f, b_ih_b, b_hh_b, w_proj,
        em_all, hxh, hxa, flags);

    ner_viterbi_kernel<<<10, 256, 0, stream>>>(
        em_all, b_proj, start_t, end_t, trans, (int*)d_out);
}